// Round 7
// baseline (480.421 us; speedup 1.0000x reference)
//
#include <hip/hip_runtime.h>
#include <hip/hip_bf16.h>

#define NB 64     // batch
#define NV 197    // visual tokens
#define NL 64     // text tokens
#define ND 768    // input dim
#define NE 256    // embed dim

typedef __attribute__((ext_vector_type(8))) short bh8;     // 8 bf16 = 4 VGPR
typedef __attribute__((ext_vector_type(16))) float f32x16; // MFMA 32x32 accum

__device__ inline ushort f2bf(float x) {
  __hip_bfloat16 h = __float2bfloat16(x);
  return *reinterpret_cast<ushort*>(&h);
}

__device__ inline bh8 cvt8(float4 a, float4 b) {
  union { bh8 v; ushort u[8]; } r;
  r.u[0] = f2bf(a.x); r.u[1] = f2bf(a.y); r.u[2] = f2bf(a.z); r.u[3] = f2bf(a.w);
  r.u[4] = f2bf(b.x); r.u[5] = f2bf(b.y); r.u[6] = f2bf(b.z); r.u[7] = f2bf(b.w);
  return r.v;
}

// ---------- Kernel 0: W -> bf16 MFMA-fragment order (verified R6) ----------
__global__ __launch_bounds__(256) void wcvt_kernel(
    const float* __restrict__ W0, const float* __restrict__ W1,
    const float* __restrict__ W2, const float* __restrict__ W3,
    ushort* __restrict__ O0, ushort* __restrict__ O1,
    ushort* __restrict__ O2, ushort* __restrict__ O3) {
  const float* Win; ushort* Wout;
  switch (blockIdx.y) {
    case 0: Win = W0; Wout = O0; break;
    case 1: Win = W1; Wout = O1; break;
    case 2: Win = W2; Wout = O2; break;
    default: Win = W3; Wout = O3; break;
  }
  const int ks = blockIdx.x;        // 0..47
  const int t = threadIdx.x;
  const int l = t & 63;
  const int lr = l & 31, hi = l >> 5;
  const int kbase = ks * 16 + hi * 8;
#pragma unroll
  for (int i = 0; i < 2; ++i) {
    const int nt = (t >> 6) + i * 4;        // 0..7
    const int n = nt * 32 + lr;
    union { bh8 v; ushort u[8]; } f;
#pragma unroll
    for (int e = 0; e < 8; ++e)
      f.u[e] = f2bf(Win[(size_t)(kbase + e) * NE + n]);   // coalesced over lr
    *(bh8*)&Wout[(size_t)((nt * 48 + ks) * 64 + l) * 8] = f.v;  // coalesced
  }
}

// ---------- Kernel 1: unified projection (tok + cls) via MFMA ----------
// Verified R6 structure. New: t_tok blocks write output in A-FRAGMENT order
// so sim can stage T->LDS with a linear copy.
// Frag index for element (t=wr*32+R, k=wc*128+i*32+lr) within q's 16384:
//   ((wr*16 + wc*8 + i*2 + (lr>>4))*64 + R + 32*((lr>>3)&1))*8 + (lr&7)
__global__ __launch_bounds__(256, 2) void proj_kernel(
    const float* __restrict__ Xv, const float* __restrict__ Xt,
    const float* __restrict__ Xcv, const float* __restrict__ Xct,
    const ushort* __restrict__ Fv, const ushort* __restrict__ Ft,
    const ushort* __restrict__ Fcv, const ushort* __restrict__ Fct,
    const float* __restrict__ bvt, const float* __restrict__ btt,
    const float* __restrict__ bv, const float* __restrict__ bt,
    ushort* __restrict__ v_tok, ushort* __restrict__ t_frag,
    float* __restrict__ v_cls, float* __restrict__ t_cls) {
  __shared__ float a_lds[64 * 64];       // 16 KB, swizzled
  __shared__ float ssq_lds[2][2][32];    // [wc][wr][row]

  const int blk = blockIdx.x;
  const float* X; const ushort* F; const float* bias;
  ushort* outb = nullptr; float* outf = nullptr;
  int row0; bool norm; bool tfrag = false;
  if (blk < 197)       { X = Xv;  F = Fv;  bias = bvt; outb = v_tok;  row0 = blk * 64;         norm = true; }
  else if (blk < 261)  { X = Xt;  F = Ft;  bias = btt; outb = t_frag; row0 = (blk - 197) * 64; norm = true; tfrag = true; }
  else if (blk == 261) { X = Xcv; F = Fcv; bias = bv;  outf = v_cls;  row0 = 0;                norm = false; }
  else                 { X = Xct; F = Fct; bias = bt;  outf = t_cls;  row0 = 0;                norm = false; }

  const int t = threadIdx.x;
  const int l = t & 63, w = t >> 6;
  const int lr = l & 31, hi = l >> 5;
  const int wr = w & 1, wc = w >> 1;

  const int srow = t >> 2;
  const int scq = t & 3;
  const float* Xrow = X + (size_t)(row0 + srow) * ND;

  const int arow = wr * 32 + lr;
  const ushort* Fw = F + ((size_t)(wc * 4 * 48) * 64 + l) * 8;

  f32x16 acc0 = {0}, acc1 = {0}, acc2 = {0}, acc3 = {0};

  float4 g0, g1, g2, g3, n0, n1, n2, n3;
#define GLOAD(d0, d1, d2, d3, kc) \
  d0 = *(const float4*)(Xrow + (kc) + scq * 4); \
  d1 = *(const float4*)(Xrow + (kc) + 16 + scq * 4); \
  d2 = *(const float4*)(Xrow + (kc) + 32 + scq * 4); \
  d3 = *(const float4*)(Xrow + (kc) + 48 + scq * 4);

  // swizzled fp32 A-tile float-index
#define ASWZ(row, cbyte) ((((row) * 256 + (cbyte)) ^ (((row) & 15) << 4)) >> 2)

  GLOAD(g0, g1, g2, g3, 0)
  for (int c = 0; c < 12; ++c) {
    if (c) __syncthreads();
    *(float4*)&a_lds[ASWZ(srow, scq * 16)]       = g0;
    *(float4*)&a_lds[ASWZ(srow, 64 + scq * 16)]  = g1;
    *(float4*)&a_lds[ASWZ(srow, 128 + scq * 16)] = g2;
    *(float4*)&a_lds[ASWZ(srow, 192 + scq * 16)] = g3;
    if (c < 11) { GLOAD(n0, n1, n2, n3, (c + 1) * 64) }
    __syncthreads();

#pragma unroll
    for (int ksl = 0; ksl < 4; ++ksl) {
      const int ks = c * 4 + ksl;
      float4 af0 = *(const float4*)&a_lds[ASWZ(arow, ksl * 64 + hi * 32)];
      float4 af1 = *(const float4*)&a_lds[ASWZ(arow, ksl * 64 + hi * 32 + 16)];
      bh8 b0 = *(const bh8*)(Fw + (size_t)(0 * 48 + ks) * 64 * 8);
      bh8 b1 = *(const bh8*)(Fw + (size_t)(1 * 48 + ks) * 64 * 8);
      bh8 b2 = *(const bh8*)(Fw + (size_t)(2 * 48 + ks) * 64 * 8);
      bh8 b3 = *(const bh8*)(Fw + (size_t)(3 * 48 + ks) * 64 * 8);
      bh8 af = cvt8(af0, af1);
      acc0 = __builtin_amdgcn_mfma_f32_32x32x16_bf16(af, b0, acc0, 0, 0, 0);
      acc1 = __builtin_amdgcn_mfma_f32_32x32x16_bf16(af, b1, acc1, 0, 0, 0);
      acc2 = __builtin_amdgcn_mfma_f32_32x32x16_bf16(af, b2, acc2, 0, 0, 0);
      acc3 = __builtin_amdgcn_mfma_f32_32x32x16_bf16(af, b3, acc3, 0, 0, 0);
    }
    g0 = n0; g1 = n1; g2 = n2; g3 = n3;
  }
#undef GLOAD
#undef ASWZ

  const float bn0 = bias[wc * 128 + lr];
  const float bn1 = bias[wc * 128 + 32 + lr];
  const float bn2 = bias[wc * 128 + 64 + lr];
  const float bn3 = bias[wc * 128 + 96 + lr];
#pragma unroll
  for (int r = 0; r < 16; ++r) {
    acc0[r] += bn0; acc1[r] += bn1; acc2[r] += bn2; acc3[r] += bn3;
  }

  if (norm) {
    float p[16];
#pragma unroll
    for (int r = 0; r < 16; ++r)
      p[r] = acc0[r] * acc0[r] + acc1[r] * acc1[r] +
             acc2[r] * acc2[r] + acc3[r] * acc3[r];
#pragma unroll
    for (int off = 1; off < 32; off <<= 1) {
#pragma unroll
      for (int r = 0; r < 16; ++r) p[r] += __shfl_xor(p[r], off);
    }
    if (lr == 0) {
#pragma unroll
      for (int r = 0; r < 16; ++r)
        ssq_lds[wc][wr][(r & 3) + 8 * (r >> 2) + 4 * hi] = p[r];
    }
    __syncthreads();
    if (!tfrag) {
#pragma unroll
      for (int r = 0; r < 16; ++r) {
        const int R = (r & 3) + 8 * (r >> 2) + 4 * hi;
        const float s = ssq_lds[0][wr][R] + ssq_lds[1][wr][R];
        const float scale = 1.0f / fmaxf(sqrtf(s), 1e-12f);
        ushort* orow = outb + (size_t)(row0 + wr * 32 + R) * NE + wc * 128 + lr;
        orow[0]  = f2bf(acc0[r] * scale);
        orow[32] = f2bf(acc1[r] * scale);
        orow[64] = f2bf(acc2[r] * scale);
        orow[96] = f2bf(acc3[r] * scale);
      }
    } else {
      ushort* tq = outb + (size_t)(row0 >> 6) * 16384;   // q = blk-197
      const int cA = lr >> 4;
      const int cB = ((lr >> 3) & 1) * 32;
      const int cE = lr & 7;
#pragma unroll
      for (int r = 0; r < 16; ++r) {
        const int R = (r & 3) + 8 * (r >> 2) + 4 * hi;
        const float s = ssq_lds[0][wr][R] + ssq_lds[1][wr][R];
        const float scale = 1.0f / fmaxf(sqrtf(s), 1e-12f);
        const int base = ((wr * 16 + wc * 8 + cA) * 64 + R + cB) * 8 + cE;
        tq[base]        = f2bf(acc0[r] * scale);
        tq[base + 1024] = f2bf(acc1[r] * scale);   // i=1: +2*512
        tq[base + 2048] = f2bf(acc2[r] * scale);
        tq[base + 3072] = f2bf(acc3[r] * scale);
      }
    }
  } else {
#pragma unroll
    for (int r = 0; r < 16; ++r) {
      const int R = (r & 3) + 8 * (r >> 2) + 4 * hi;
      float* orow = outf + (size_t)(row0 + wr * 32 + R) * NE + wc * 128 + lr;
      orow[0]  = acc0[r];
      orow[32] = acc1[r];
      orow[64] = acc2[r];
      orow[96] = acc3[r];
    }
  }
}

// ---------- Kernel 2: chamfer similarity, one wave per (b,q) pair ----------
// Swapped operands: mfma(A=T frag, B=V frag) -> D[row=t][col=v].
// T[q] in LDS (frag order, staged by linear copy). V streamed as B-frags
// with 4-deep ring. i2t: in-lane max over t + 1 shfl. t2i: running in-lane
// max over v-tiles, single lr-butterfly per pair.
__global__ __launch_bounds__(256, 3) void sim_kernel(
    const ushort* __restrict__ vt, const ushort* __restrict__ tfrag,
    const int* __restrict__ tlen,
    float* __restrict__ out_i2t, float* __restrict__ out_t2i) {
  __shared__ ushort t_lds[16384];   // 32 KB: [mt(2)][ks(16)][lane(64)][e(8)]

  const int blk = blockIdx.x;
  const int q = blk & 63;
  const int bc = blk >> 6;          // 0..15
  const int tid = threadIdx.x;

  {  // stage T: frag-order global -> LDS, linear, coalesced, conflict-free
    const bh8* src = (const bh8*)(tfrag + (size_t)q * 16384);
    bh8* dst = (bh8*)t_lds;
#pragma unroll
    for (int j = 0; j < 8; ++j) dst[tid + j * 256] = src[tid + j * 256];
  }
  __syncthreads();

  const int l = tid & 63, w = tid >> 6;
  const int lr = l & 31, hi = l >> 5;
  const int b = bc * 4 + w;
  const int len = tlen[b];
  const ushort* Vb = vt + (size_t)b * NV * NE + hi * 8;

  // per-v-tile row offsets (clamped to row 196 for pad rows)
  int offA[4], offB[4];
#pragma unroll
  for (int p = 0; p < 4; ++p) {
    offA[p] = min(p * 64 + lr, NV - 1) * NE;
    offB[p] = min(p * 64 + 32 + lr, NV - 1) * NE;
  }

  bh8 rA[4], rB[4];
#pragma unroll
  for (int s = 0; s < 4; ++s) {
    rA[s] = *(const bh8*)(Vb + offA[0] + s * 16);
    rB[s] = *(const bh8*)(Vb + offB[0] + s * 16);
  }

  f32x16 vmax0, vmax1;
#pragma unroll
  for (int r = 0; r < 16; ++r) { vmax0[r] = -1e30f; vmax1[r] = -1e30f; }
  float i2t_sum = 0.0f;

#pragma unroll
  for (int p = 0; p < 4; ++p) {
    f32x16 a00 = {0}, a01 = {0}, a10 = {0}, a11 = {0};  // [mt][st]
    __builtin_amdgcn_s_setprio(1);
#pragma unroll
    for (int ks = 0; ks < 16; ++ks) {
      bh8 ta0 = *(const bh8*)&t_lds[(size_t)(ks * 64 + l) * 8];
      bh8 ta1 = *(const bh8*)&t_lds[(size_t)((16 + ks) * 64 + l) * 8];
      bh8 vb0 = rA[ks & 3], vb1 = rB[ks & 3];
      int sn = p * 16 + ks + 4; if (sn > 63) sn = 63;   // clamp: tail refills unused
      const int p2 = sn >> 4, k2 = sn & 15;             // compile-time post-unroll
      rA[ks & 3] = *(const bh8*)(Vb + offA[p2] + k2 * 16);
      rB[ks & 3] = *(const bh8*)(Vb + offB[p2] + k2 * 16);
      a00 = __builtin_amdgcn_mfma_f32_32x32x16_bf16(ta0, vb0, a00, 0, 0, 0);
      a01 = __builtin_amdgcn_mfma_f32_32x32x16_bf16(ta0, vb1, a01, 0, 0, 0);
      a10 = __builtin_amdgcn_mfma_f32_32x32x16_bf16(ta1, vb0, a10, 0, 0, 0);
      a11 = __builtin_amdgcn_mfma_f32_32x32x16_bf16(ta1, vb1, a11, 0, 0, 0);
    }
    __builtin_amdgcn_s_setprio(0);

    // i2t: per-lane v-col, max over t (in-lane 32 els + cross-hi)
    {
      float m0 = fmaxf(a00[0], a10[0]);
#pragma unroll
      for (int r = 1; r < 16; ++r) m0 = fmaxf(m0, fmaxf(a00[r], a10[r]));
      m0 = fmaxf(m0, __shfl_xor(m0, 32));
      if ((p * 64 + lr) < NV && hi == 0) i2t_sum += m0;
      float m1 = fmaxf(a01[0], a11[0]);
#pragma unroll
      for (int r = 1; r < 16; ++r) m1 = fmaxf(m1, fmaxf(a01[r], a11[r]));
      m1 = fmaxf(m1, __shfl_xor(m1, 32));
      if ((p * 64 + 32 + lr) < NV && hi == 0) i2t_sum += m1;
    }
    // t2i: running max over v (clamped dup rows can't change the max)
#pragma unroll
    for (int r = 0; r < 16; ++r) {
      vmax0[r] = fmaxf(vmax0[r], fmaxf(a00[r], a01[r]));
      vmax1[r] = fmaxf(vmax1[r], fmaxf(a10[r], a11[r]));
    }
  }

  // t2i finalize: one lr-butterfly per pair
#pragma unroll
  for (int off = 1; off < 32; off <<= 1) {
#pragma unroll
    for (int r = 0; r < 16; ++r) {
      vmax0[r] = fmaxf(vmax0[r], __shfl_xor(vmax0[r], off));
      vmax1[r] = fmaxf(vmax1[r], __shfl_xor(vmax1[r], off));
    }
  }
  float tsum = 0.0f;
#pragma unroll
  for (int r = 0; r < 16; ++r) {
    const int t0 = (r & 3) + 8 * (r >> 2) + 4 * hi;
    if (t0 < len) tsum += vmax0[r];
    if (32 + t0 < len) tsum += vmax1[r];
  }
  tsum += __shfl_xor(tsum, 32);

#pragma unroll
  for (int off = 1; off < 64; off <<= 1) i2t_sum += __shfl_xor(i2t_sum, off);

  if (l == 0) {
    out_t2i[b * NB + q] = tsum / fmaxf((float)len, 1e-6f);
    out_i2t[b * NB + q] = i2t_sum / (float)NV;
  }
}

extern "C" void kernel_launch(void* const* d_in, const int* in_sizes, int n_in,
                              void* d_out, int out_size, void* d_ws, size_t ws_size,
                              hipStream_t stream) {
  (void)in_sizes; (void)n_in; (void)out_size; (void)ws_size;
  const float* visual_cls    = (const float*)d_in[0];
  const float* textual_cls   = (const float*)d_in[1];
  const float* visual_tokens = (const float*)d_in[2];
  const float* textual_tokens= (const float*)d_in[3];
  const int*   text_length   = (const int*)d_in[4];
  const float* Wv  = (const float*)d_in[5];
  const float* bv  = (const float*)d_in[6];
  const float* Wt  = (const float*)d_in[7];
  const float* bt  = (const float*)d_in[8];
  const float* Wvt = (const float*)d_in[9];
  const float* bvt = (const float*)d_in[10];
  const float* Wtt = (const float*)d_in[11];
  const float* btt = (const float*)d_in[12];

  float* out   = (float*)d_out;
  float* v_cls = out;                       // 64*256
  float* t_cls = out + NB * NE;             // 64*256
  float* i2t   = out + 2 * NB * NE;         // 64*64
  float* t2i   = i2t + NB * NB;             // 64*64

  ushort* wsb    = (ushort*)d_ws;
  ushort* v_tok  = wsb;                                  // 12608*256 bf16
  ushort* t_frag = v_tok + (size_t)NB * NV * NE;         // 64 q * 16384 (frag order)
  ushort* Fv     = t_frag + (size_t)NB * NL * NE;        // 8*48*64*8 each
  ushort* Ft     = Fv + (size_t)8 * 48 * 64 * 8;
  ushort* Fcv    = Ft + (size_t)8 * 48 * 64 * 8;
  ushort* Fct    = Fcv + (size_t)8 * 48 * 64 * 8;

  wcvt_kernel<<<dim3(48, 4), 256, 0, stream>>>(Wvt, Wtt, Wv, Wt,
                                               Fv, Ft, Fcv, Fct);
  proj_kernel<<<263, 256, 0, stream>>>(visual_tokens, textual_tokens,
                                       visual_cls, textual_cls,
                                       Fv, Ft, Fcv, Fct,
                                       bvt, btt, bv, bt,
                                       v_tok, t_frag, v_cls, t_cls);
  sim_kernel<<<NB * NB / 4, 256, 0, stream>>>(v_tok, t_frag,
                                              text_length, i2t, t2i);
}

// Round 8
// 281.527 us; speedup vs baseline: 1.7065x; 1.7065x over previous
//
#include <hip/hip_runtime.h>
#include <hip/hip_bf16.h>

#define NB 64     // batch
#define NV 197    // visual tokens
#define NL 64     // text tokens
#define ND 768    // input dim
#define NE 256    // embed dim

typedef __attribute__((ext_vector_type(8))) short bh8;     // 8 bf16 = 4 VGPR
typedef __attribute__((ext_vector_type(16))) float f32x16; // MFMA 32x32 accum

__device__ inline ushort f2bf(float x) {
  __hip_bfloat16 h = __float2bfloat16(x);
  return *reinterpret_cast<ushort*>(&h);
}

__device__ inline bh8 cvt8(float4 a, float4 b) {
  union { bh8 v; ushort u[8]; } r;
  r.u[0] = f2bf(a.x); r.u[1] = f2bf(a.y); r.u[2] = f2bf(a.z); r.u[3] = f2bf(a.w);
  r.u[4] = f2bf(b.x); r.u[5] = f2bf(b.y); r.u[6] = f2bf(b.z); r.u[7] = f2bf(b.w);
  return r.v;
}

// ---------- Kernel 0: W -> bf16 MFMA-fragment order (verified R6) ----------
__global__ __launch_bounds__(256) void wcvt_kernel(
    const float* __restrict__ W0, const float* __restrict__ W1,
    const float* __restrict__ W2, const float* __restrict__ W3,
    ushort* __restrict__ O0, ushort* __restrict__ O1,
    ushort* __restrict__ O2, ushort* __restrict__ O3) {
  const float* Win; ushort* Wout;
  switch (blockIdx.y) {
    case 0: Win = W0; Wout = O0; break;
    case 1: Win = W1; Wout = O1; break;
    case 2: Win = W2; Wout = O2; break;
    default: Win = W3; Wout = O3; break;
  }
  const int ks = blockIdx.x;        // 0..47
  const int t = threadIdx.x;
  const int l = t & 63;
  const int lr = l & 31, hi = l >> 5;
  const int kbase = ks * 16 + hi * 8;
#pragma unroll
  for (int i = 0; i < 2; ++i) {
    const int nt = (t >> 6) + i * 4;        // 0..7
    const int n = nt * 32 + lr;
    union { bh8 v; ushort u[8]; } f;
#pragma unroll
    for (int e = 0; e < 8; ++e)
      f.u[e] = f2bf(Win[(size_t)(kbase + e) * NE + n]);   // coalesced over lr
    *(bh8*)&Wout[(size_t)((nt * 48 + ks) * 64 + l) * 8] = f.v;  // coalesced
  }
}

// ---------- Kernel 1: unified projection (tok + cls) via MFMA ----------
// Verified R6/R7 structure; t_tok written in A-FRAGMENT order for sim.
__global__ __launch_bounds__(256, 2) void proj_kernel(
    const float* __restrict__ Xv, const float* __restrict__ Xt,
    const float* __restrict__ Xcv, const float* __restrict__ Xct,
    const ushort* __restrict__ Fv, const ushort* __restrict__ Ft,
    const ushort* __restrict__ Fcv, const ushort* __restrict__ Fct,
    const float* __restrict__ bvt, const float* __restrict__ btt,
    const float* __restrict__ bv, const float* __restrict__ bt,
    ushort* __restrict__ v_tok, ushort* __restrict__ t_frag,
    float* __restrict__ v_cls, float* __restrict__ t_cls) {
  __shared__ float a_lds[64 * 64];       // 16 KB, swizzled
  __shared__ float ssq_lds[2][2][32];    // [wc][wr][row]

  const int blk = blockIdx.x;
  const float* X; const ushort* F; const float* bias;
  ushort* outb = nullptr; float* outf = nullptr;
  int row0; bool norm; bool tfrag = false;
  if (blk < 197)       { X = Xv;  F = Fv;  bias = bvt; outb = v_tok;  row0 = blk * 64;         norm = true; }
  else if (blk < 261)  { X = Xt;  F = Ft;  bias = btt; outb = t_frag; row0 = (blk - 197) * 64; norm = true; tfrag = true; }
  else if (blk == 261) { X = Xcv; F = Fcv; bias = bv;  outf = v_cls;  row0 = 0;                norm = false; }
  else                 { X = Xct; F = Fct; bias = bt;  outf = t_cls;  row0 = 0;                norm = false; }

  const int t = threadIdx.x;
  const int l = t & 63, w = t >> 6;
  const int lr = l & 31, hi = l >> 5;
  const int wr = w & 1, wc = w >> 1;

  const int srow = t >> 2;
  const int scq = t & 3;
  const float* Xrow = X + (size_t)(row0 + srow) * ND;

  const int arow = wr * 32 + lr;
  const ushort* Fw = F + ((size_t)(wc * 4 * 48) * 64 + l) * 8;

  f32x16 acc0 = {0}, acc1 = {0}, acc2 = {0}, acc3 = {0};

  float4 g0, g1, g2, g3, n0, n1, n2, n3;
#define GLOAD(d0, d1, d2, d3, kc) \
  d0 = *(const float4*)(Xrow + (kc) + scq * 4); \
  d1 = *(const float4*)(Xrow + (kc) + 16 + scq * 4); \
  d2 = *(const float4*)(Xrow + (kc) + 32 + scq * 4); \
  d3 = *(const float4*)(Xrow + (kc) + 48 + scq * 4);

#define ASWZ(row, cbyte) ((((row) * 256 + (cbyte)) ^ (((row) & 15) << 4)) >> 2)

  GLOAD(g0, g1, g2, g3, 0)
  for (int c = 0; c < 12; ++c) {
    if (c) __syncthreads();
    *(float4*)&a_lds[ASWZ(srow, scq * 16)]       = g0;
    *(float4*)&a_lds[ASWZ(srow, 64 + scq * 16)]  = g1;
    *(float4*)&a_lds[ASWZ(srow, 128 + scq * 16)] = g2;
    *(float4*)&a_lds[ASWZ(srow, 192 + scq * 16)] = g3;
    if (c < 11) { GLOAD(n0, n1, n2, n3, (c + 1) * 64) }
    __syncthreads();

#pragma unroll
    for (int ksl = 0; ksl < 4; ++ksl) {
      const int ks = c * 4 + ksl;
      float4 af0 = *(const float4*)&a_lds[ASWZ(arow, ksl * 64 + hi * 32)];
      float4 af1 = *(const float4*)&a_lds[ASWZ(arow, ksl * 64 + hi * 32 + 16)];
      bh8 b0 = *(const bh8*)(Fw + (size_t)(0 * 48 + ks) * 64 * 8);
      bh8 b1 = *(const bh8*)(Fw + (size_t)(1 * 48 + ks) * 64 * 8);
      bh8 b2 = *(const bh8*)(Fw + (size_t)(2 * 48 + ks) * 64 * 8);
      bh8 b3 = *(const bh8*)(Fw + (size_t)(3 * 48 + ks) * 64 * 8);
      bh8 af = cvt8(af0, af1);
      acc0 = __builtin_amdgcn_mfma_f32_32x32x16_bf16(af, b0, acc0, 0, 0, 0);
      acc1 = __builtin_amdgcn_mfma_f32_32x32x16_bf16(af, b1, acc1, 0, 0, 0);
      acc2 = __builtin_amdgcn_mfma_f32_32x32x16_bf16(af, b2, acc2, 0, 0, 0);
      acc3 = __builtin_amdgcn_mfma_f32_32x32x16_bf16(af, b3, acc3, 0, 0, 0);
    }
    g0 = n0; g1 = n1; g2 = n2; g3 = n3;
  }
#undef GLOAD
#undef ASWZ

  const float bn0 = bias[wc * 128 + lr];
  const float bn1 = bias[wc * 128 + 32 + lr];
  const float bn2 = bias[wc * 128 + 64 + lr];
  const float bn3 = bias[wc * 128 + 96 + lr];
#pragma unroll
  for (int r = 0; r < 16; ++r) {
    acc0[r] += bn0; acc1[r] += bn1; acc2[r] += bn2; acc3[r] += bn3;
  }

  if (norm) {
    float p[16];
#pragma unroll
    for (int r = 0; r < 16; ++r)
      p[r] = acc0[r] * acc0[r] + acc1[r] * acc1[r] +
             acc2[r] * acc2[r] + acc3[r] * acc3[r];
#pragma unroll
    for (int off = 1; off < 32; off <<= 1) {
#pragma unroll
      for (int r = 0; r < 16; ++r) p[r] += __shfl_xor(p[r], off);
    }
    if (lr == 0) {
#pragma unroll
      for (int r = 0; r < 16; ++r)
        ssq_lds[wc][wr][(r & 3) + 8 * (r >> 2) + 4 * hi] = p[r];
    }
    __syncthreads();
    if (!tfrag) {
#pragma unroll
      for (int r = 0; r < 16; ++r) {
        const int R = (r & 3) + 8 * (r >> 2) + 4 * hi;
        const float s = ssq_lds[0][wr][R] + ssq_lds[1][wr][R];
        const float scale = 1.0f / fmaxf(sqrtf(s), 1e-12f);
        ushort* orow = outb + (size_t)(row0 + wr * 32 + R) * NE + wc * 128 + lr;
        orow[0]  = f2bf(acc0[r] * scale);
        orow[32] = f2bf(acc1[r] * scale);
        orow[64] = f2bf(acc2[r] * scale);
        orow[96] = f2bf(acc3[r] * scale);
      }
    } else {
      ushort* tq = outb + (size_t)(row0 >> 6) * 16384;   // q = blk-197
      const int cA = lr >> 4;
      const int cB = ((lr >> 3) & 1) * 32;
      const int cE = lr & 7;
#pragma unroll
      for (int r = 0; r < 16; ++r) {
        const int R = (r & 3) + 8 * (r >> 2) + 4 * hi;
        const float s = ssq_lds[0][wr][R] + ssq_lds[1][wr][R];
        const float scale = 1.0f / fmaxf(sqrtf(s), 1e-12f);
        const int base = ((wr * 16 + wc * 8 + cA) * 64 + R + cB) * 8 + cE;
        tq[base]        = f2bf(acc0[r] * scale);
        tq[base + 1024] = f2bf(acc1[r] * scale);
        tq[base + 2048] = f2bf(acc2[r] * scale);
        tq[base + 3072] = f2bf(acc3[r] * scale);
      }
    }
  } else {
#pragma unroll
    for (int r = 0; r < 16; ++r) {
      const int R = (r & 3) + 8 * (r >> 2) + 4 * hi;
      float* orow = outf + (size_t)(row0 + wr * 32 + R) * NE + wc * 128 + lr;
      orow[0]  = acc0[r];
      orow[32] = acc1[r];
      orow[64] = acc2[r];
      orow[96] = acc3[r];
    }
  }
}

// ---------- Kernel 2: chamfer similarity, one wave per (b,q) pair ----------
// R7-verified structure. FIX: launch_bounds (256,3)->(256,2). The 3-wave cap
// (~170 VGPR) spilled the f32x16 accumulators to scratch (R7 counters:
// VGPR=84, 850 MB/dispatch HBM spill traffic, MfmaUtil 4%). At 2 waves/SIMD
// the ~160-reg live set fits.
__global__ __launch_bounds__(256, 2) void sim_kernel(
    const ushort* __restrict__ vt, const ushort* __restrict__ tfrag,
    const int* __restrict__ tlen,
    float* __restrict__ out_i2t, float* __restrict__ out_t2i) {
  __shared__ ushort t_lds[16384];   // 32 KB: [mt(2)][ks(16)][lane(64)][e(8)]

  const int blk = blockIdx.x;
  const int q = blk & 63;
  const int bc = blk >> 6;          // 0..15
  const int tid = threadIdx.x;

  {  // stage T: frag-order global -> LDS, linear, coalesced, conflict-free
    const bh8* src = (const bh8*)(tfrag + (size_t)q * 16384);
    bh8* dst = (bh8*)t_lds;
#pragma unroll
    for (int j = 0; j < 8; ++j) dst[tid + j * 256] = src[tid + j * 256];
  }
  __syncthreads();

  const int l = tid & 63, w = tid >> 6;
  const int lr = l & 31, hi = l >> 5;
  const int b = bc * 4 + w;
  const int len = tlen[b];
  const ushort* Vb = vt + (size_t)b * NV * NE + hi * 8;

  // per-v-tile row offsets (clamped to row 196 for pad rows)
  int offA[4], offB[4];
#pragma unroll
  for (int p = 0; p < 4; ++p) {
    offA[p] = min(p * 64 + lr, NV - 1) * NE;
    offB[p] = min(p * 64 + 32 + lr, NV - 1) * NE;
  }

  bh8 rA[4], rB[4];
#pragma unroll
  for (int s = 0; s < 4; ++s) {
    rA[s] = *(const bh8*)(Vb + offA[0] + s * 16);
    rB[s] = *(const bh8*)(Vb + offB[0] + s * 16);
  }

  f32x16 vmax0, vmax1;
#pragma unroll
  for (int r = 0; r < 16; ++r) { vmax0[r] = -1e30f; vmax1[r] = -1e30f; }
  float i2t_sum = 0.0f;

#pragma unroll
  for (int p = 0; p < 4; ++p) {
    f32x16 a00 = {0}, a01 = {0}, a10 = {0}, a11 = {0};  // [mt][st]
    __builtin_amdgcn_s_setprio(1);
#pragma unroll
    for (int ks = 0; ks < 16; ++ks) {
      bh8 ta0 = *(const bh8*)&t_lds[(size_t)(ks * 64 + l) * 8];
      bh8 ta1 = *(const bh8*)&t_lds[(size_t)((16 + ks) * 64 + l) * 8];
      bh8 vb0 = rA[ks & 3], vb1 = rB[ks & 3];
      int sn = p * 16 + ks + 4; if (sn > 63) sn = 63;   // clamp: tail refills unused
      const int p2 = sn >> 4, k2 = sn & 15;             // compile-time post-unroll
      rA[ks & 3] = *(const bh8*)(Vb + offA[p2] + k2 * 16);
      rB[ks & 3] = *(const bh8*)(Vb + offB[p2] + k2 * 16);
      a00 = __builtin_amdgcn_mfma_f32_32x32x16_bf16(ta0, vb0, a00, 0, 0, 0);
      a01 = __builtin_amdgcn_mfma_f32_32x32x16_bf16(ta0, vb1, a01, 0, 0, 0);
      a10 = __builtin_amdgcn_mfma_f32_32x32x16_bf16(ta1, vb0, a10, 0, 0, 0);
      a11 = __builtin_amdgcn_mfma_f32_32x32x16_bf16(ta1, vb1, a11, 0, 0, 0);
    }
    __builtin_amdgcn_s_setprio(0);

    // i2t: per-lane v-col, max over t (in-lane 32 els + cross-hi)
    {
      float m0 = fmaxf(a00[0], a10[0]);
#pragma unroll
      for (int r = 1; r < 16; ++r) m0 = fmaxf(m0, fmaxf(a00[r], a10[r]));
      m0 = fmaxf(m0, __shfl_xor(m0, 32));
      if ((p * 64 + lr) < NV && hi == 0) i2t_sum += m0;
      float m1 = fmaxf(a01[0], a11[0]);
#pragma unroll
      for (int r = 1; r < 16; ++r) m1 = fmaxf(m1, fmaxf(a01[r], a11[r]));
      m1 = fmaxf(m1, __shfl_xor(m1, 32));
      if ((p * 64 + 32 + lr) < NV && hi == 0) i2t_sum += m1;
    }
    // t2i: running max over v (clamped dup rows can't change the max)
#pragma unroll
    for (int r = 0; r < 16; ++r) {
      vmax0[r] = fmaxf(vmax0[r], fmaxf(a00[r], a01[r]));
      vmax1[r] = fmaxf(vmax1[r], fmaxf(a10[r], a11[r]));
    }
  }

  // t2i finalize: one lr-butterfly per pair
#pragma unroll
  for (int off = 1; off < 32; off <<= 1) {
#pragma unroll
    for (int r = 0; r < 16; ++r) {
      vmax0[r] = fmaxf(vmax0[r], __shfl_xor(vmax0[r], off));
      vmax1[r] = fmaxf(vmax1[r], __shfl_xor(vmax1[r], off));
    }
  }
  float tsum = 0.0f;
#pragma unroll
  for (int r = 0; r < 16; ++r) {
    const int t0 = (r & 3) + 8 * (r >> 2) + 4 * hi;
    if (t0 < len) tsum += vmax0[r];
    if (32 + t0 < len) tsum += vmax1[r];
  }
  tsum += __shfl_xor(tsum, 32);

#pragma unroll
  for (int off = 1; off < 64; off <<= 1) i2t_sum += __shfl_xor(i2t_sum, off);

  if (l == 0) {
    out_t2i[b * NB + q] = tsum / fmaxf((float)len, 1e-6f);
    out_i2t[b * NB + q] = i2t_sum / (float)NV;
  }
}

extern "C" void kernel_launch(void* const* d_in, const int* in_sizes, int n_in,
                              void* d_out, int out_size, void* d_ws, size_t ws_size,
                              hipStream_t stream) {
  (void)in_sizes; (void)n_in; (void)out_size; (void)ws_size;
  const float* visual_cls    = (const float*)d_in[0];
  const float* textual_cls   = (const float*)d_in[1];
  const float* visual_tokens = (const float*)d_in[2];
  const float* textual_tokens= (const float*)d_in[3];
  const int*   text_length   = (const int*)d_in[4];
  const float* Wv  = (const float*)d_in[5];
  const float* bv  = (const float*)d_in[6];
  const float* Wt  = (const float*)d_in[7];
  const float* bt  = (const float*)d_in[8];
  const float* Wvt = (const float*)d_in[9];
  const float* bvt = (const float*)d_in[10];
  const float* Wtt = (const float*)d_in[11];
  const float* btt = (const float*)d_in[12];

  float* out   = (float*)d_out;
  float* v_cls = out;                       // 64*256
  float* t_cls = out + NB * NE;             // 64*256
  float* i2t   = out + 2 * NB * NE;         // 64*64
  float* t2i   = i2t + NB * NB;             // 64*64

  ushort* wsb    = (ushort*)d_ws;
  ushort* v_tok  = wsb;                                  // 12608*256 bf16
  ushort* t_frag = v_tok + (size_t)NB * NV * NE;         // 64 q * 16384 (frag order)
  ushort* Fv     = t_frag + (size_t)NB * NL * NE;        // 8*48*64*8 each
  ushort* Ft     = Fv + (size_t)8 * 48 * 64 * 8;
  ushort* Fcv    = Ft + (size_t)8 * 48 * 64 * 8;
  ushort* Fct    = Fcv + (size_t)8 * 48 * 64 * 8;

  wcvt_kernel<<<dim3(48, 4), 256, 0, stream>>>(Wvt, Wtt, Wv, Wt,
                                               Fv, Ft, Fcv, Fct);
  proj_kernel<<<263, 256, 0, stream>>>(visual_tokens, textual_tokens,
                                       visual_cls, textual_cls,
                                       Fv, Ft, Fcv, Fct,
                                       bvt, btt, bv, bt,
                                       v_tok, t_frag, v_cls, t_cls);
  sim_kernel<<<NB * NB / 4, 256, 0, stream>>>(v_tok, t_frag,
                                              text_length, i2t, t2i);
}

// Round 10
// 224.655 us; speedup vs baseline: 2.1385x; 1.2532x over previous
//
#include <hip/hip_runtime.h>
#include <hip/hip_bf16.h>

#define NB 64     // batch
#define NV 197    // visual tokens
#define NL 64     // text tokens
#define ND 768    // input dim
#define NE 256    // embed dim

typedef __attribute__((ext_vector_type(8))) short bh8;     // 8 bf16 = 4 VGPR
typedef __attribute__((ext_vector_type(16))) float f32x16; // MFMA 32x32 accum

__device__ inline ushort f2bf(float x) {
  __hip_bfloat16 h = __float2bfloat16(x);
  return *reinterpret_cast<ushort*>(&h);
}

__device__ inline bh8 cvt8(float4 a, float4 b) {
  union { bh8 v; ushort u[8]; } r;
  r.u[0] = f2bf(a.x); r.u[1] = f2bf(a.y); r.u[2] = f2bf(a.z); r.u[3] = f2bf(a.w);
  r.u[4] = f2bf(b.x); r.u[5] = f2bf(b.y); r.u[6] = f2bf(b.z); r.u[7] = f2bf(b.w);
  return r.v;
}

// ---------- Kernel 0: W -> bf16 MFMA-fragment order (verified R6) ----------
__global__ __launch_bounds__(256) void wcvt_kernel(
    const float* __restrict__ W0, const float* __restrict__ W1,
    const float* __restrict__ W2, const float* __restrict__ W3,
    ushort* __restrict__ O0, ushort* __restrict__ O1,
    ushort* __restrict__ O2, ushort* __restrict__ O3) {
  const float* Win; ushort* Wout;
  switch (blockIdx.y) {
    case 0: Win = W0; Wout = O0; break;
    case 1: Win = W1; Wout = O1; break;
    case 2: Win = W2; Wout = O2; break;
    default: Win = W3; Wout = O3; break;
  }
  const int ks = blockIdx.x;        // 0..47
  const int t = threadIdx.x;
  const int l = t & 63;
  const int lr = l & 31, hi = l >> 5;
  const int kbase = ks * 16 + hi * 8;
#pragma unroll
  for (int i = 0; i < 2; ++i) {
    const int nt = (t >> 6) + i * 4;        // 0..7
    const int n = nt * 32 + lr;
    union { bh8 v; ushort u[8]; } f;
#pragma unroll
    for (int e = 0; e < 8; ++e)
      f.u[e] = f2bf(Win[(size_t)(kbase + e) * NE + n]);   // coalesced over lr
    *(bh8*)&Wout[(size_t)((nt * 48 + ks) * 64 + l) * 8] = f.v;  // coalesced
  }
}

// ---------- Kernel 1: unified projection (tok + cls) via MFMA ----------
// Verified R6/R7 structure; t_tok written in A-FRAGMENT order for sim.
__global__ __launch_bounds__(256, 2) void proj_kernel(
    const float* __restrict__ Xv, const float* __restrict__ Xt,
    const float* __restrict__ Xcv, const float* __restrict__ Xct,
    const ushort* __restrict__ Fv, const ushort* __restrict__ Ft,
    const ushort* __restrict__ Fcv, const ushort* __restrict__ Fct,
    const float* __restrict__ bvt, const float* __restrict__ btt,
    const float* __restrict__ bv, const float* __restrict__ bt,
    ushort* __restrict__ v_tok, ushort* __restrict__ t_frag,
    float* __restrict__ v_cls, float* __restrict__ t_cls) {
  __shared__ float a_lds[64 * 64];       // 16 KB, swizzled
  __shared__ float ssq_lds[2][2][32];    // [wc][wr][row]

  const int blk = blockIdx.x;
  const float* X; const ushort* F; const float* bias;
  ushort* outb = nullptr; float* outf = nullptr;
  int row0; bool norm; bool tfrag = false;
  if (blk < 197)       { X = Xv;  F = Fv;  bias = bvt; outb = v_tok;  row0 = blk * 64;         norm = true; }
  else if (blk < 261)  { X = Xt;  F = Ft;  bias = btt; outb = t_frag; row0 = (blk - 197) * 64; norm = true; tfrag = true; }
  else if (blk == 261) { X = Xcv; F = Fcv; bias = bv;  outf = v_cls;  row0 = 0;                norm = false; }
  else                 { X = Xct; F = Fct; bias = bt;  outf = t_cls;  row0 = 0;                norm = false; }

  const int t = threadIdx.x;
  const int l = t & 63, w = t >> 6;
  const int lr = l & 31, hi = l >> 5;
  const int wr = w & 1, wc = w >> 1;

  const int srow = t >> 2;
  const int scq = t & 3;
  const float* Xrow = X + (size_t)(row0 + srow) * ND;

  const int arow = wr * 32 + lr;
  const ushort* Fw = F + ((size_t)(wc * 4 * 48) * 64 + l) * 8;

  f32x16 acc0 = {0}, acc1 = {0}, acc2 = {0}, acc3 = {0};

  float4 g0, g1, g2, g3, n0, n1, n2, n3;
#define GLOAD(d0, d1, d2, d3, kc) \
  d0 = *(const float4*)(Xrow + (kc) + scq * 4); \
  d1 = *(const float4*)(Xrow + (kc) + 16 + scq * 4); \
  d2 = *(const float4*)(Xrow + (kc) + 32 + scq * 4); \
  d3 = *(const float4*)(Xrow + (kc) + 48 + scq * 4);

#define ASWZ(row, cbyte) ((((row) * 256 + (cbyte)) ^ (((row) & 15) << 4)) >> 2)

  GLOAD(g0, g1, g2, g3, 0)
  for (int c = 0; c < 12; ++c) {
    if (c) __syncthreads();
    *(float4*)&a_lds[ASWZ(srow, scq * 16)]       = g0;
    *(float4*)&a_lds[ASWZ(srow, 64 + scq * 16)]  = g1;
    *(float4*)&a_lds[ASWZ(srow, 128 + scq * 16)] = g2;
    *(float4*)&a_lds[ASWZ(srow, 192 + scq * 16)] = g3;
    if (c < 11) { GLOAD(n0, n1, n2, n3, (c + 1) * 64) }
    __syncthreads();

#pragma unroll
    for (int ksl = 0; ksl < 4; ++ksl) {
      const int ks = c * 4 + ksl;
      float4 af0 = *(const float4*)&a_lds[ASWZ(arow, ksl * 64 + hi * 32)];
      float4 af1 = *(const float4*)&a_lds[ASWZ(arow, ksl * 64 + hi * 32 + 16)];
      bh8 b0 = *(const bh8*)(Fw + (size_t)(0 * 48 + ks) * 64 * 8);
      bh8 b1 = *(const bh8*)(Fw + (size_t)(1 * 48 + ks) * 64 * 8);
      bh8 b2 = *(const bh8*)(Fw + (size_t)(2 * 48 + ks) * 64 * 8);
      bh8 b3 = *(const bh8*)(Fw + (size_t)(3 * 48 + ks) * 64 * 8);
      bh8 af = cvt8(af0, af1);
      acc0 = __builtin_amdgcn_mfma_f32_32x32x16_bf16(af, b0, acc0, 0, 0, 0);
      acc1 = __builtin_amdgcn_mfma_f32_32x32x16_bf16(af, b1, acc1, 0, 0, 0);
      acc2 = __builtin_amdgcn_mfma_f32_32x32x16_bf16(af, b2, acc2, 0, 0, 0);
      acc3 = __builtin_amdgcn_mfma_f32_32x32x16_bf16(af, b3, acc3, 0, 0, 0);
    }
    g0 = n0; g1 = n1; g2 = n2; g3 = n3;
  }
#undef GLOAD
#undef ASWZ

  const float bn0 = bias[wc * 128 + lr];
  const float bn1 = bias[wc * 128 + 32 + lr];
  const float bn2 = bias[wc * 128 + 64 + lr];
  const float bn3 = bias[wc * 128 + 96 + lr];
#pragma unroll
  for (int r = 0; r < 16; ++r) {
    acc0[r] += bn0; acc1[r] += bn1; acc2[r] += bn2; acc3[r] += bn3;
  }

  if (norm) {
    float p[16];
#pragma unroll
    for (int r = 0; r < 16; ++r)
      p[r] = acc0[r] * acc0[r] + acc1[r] * acc1[r] +
             acc2[r] * acc2[r] + acc3[r] * acc3[r];
#pragma unroll
    for (int off = 1; off < 32; off <<= 1) {
#pragma unroll
      for (int r = 0; r < 16; ++r) p[r] += __shfl_xor(p[r], off);
    }
    if (lr == 0) {
#pragma unroll
      for (int r = 0; r < 16; ++r)
        ssq_lds[wc][wr][(r & 3) + 8 * (r >> 2) + 4 * hi] = p[r];
    }
    __syncthreads();
    if (!tfrag) {
#pragma unroll
      for (int r = 0; r < 16; ++r) {
        const int R = (r & 3) + 8 * (r >> 2) + 4 * hi;
        const float s = ssq_lds[0][wr][R] + ssq_lds[1][wr][R];
        const float scale = 1.0f / fmaxf(sqrtf(s), 1e-12f);
        ushort* orow = outb + (size_t)(row0 + wr * 32 + R) * NE + wc * 128 + lr;
        orow[0]  = f2bf(acc0[r] * scale);
        orow[32] = f2bf(acc1[r] * scale);
        orow[64] = f2bf(acc2[r] * scale);
        orow[96] = f2bf(acc3[r] * scale);
      }
    } else {
      ushort* tq = outb + (size_t)(row0 >> 6) * 16384;   // q = blk-197
      const int cA = lr >> 4;
      const int cB = ((lr >> 3) & 1) * 32;
      const int cE = lr & 7;
#pragma unroll
      for (int r = 0; r < 16; ++r) {
        const int R = (r & 3) + 8 * (r >> 2) + 4 * hi;
        const float s = ssq_lds[0][wr][R] + ssq_lds[1][wr][R];
        const float scale = 1.0f / fmaxf(sqrtf(s), 1e-12f);
        const int base = ((wr * 16 + wc * 8 + cA) * 64 + R + cB) * 8 + cE;
        tq[base]        = f2bf(acc0[r] * scale);
        tq[base + 1024] = f2bf(acc1[r] * scale);
        tq[base + 2048] = f2bf(acc2[r] * scale);
        tq[base + 3072] = f2bf(acc3[r] * scale);
      }
    }
  } else {
#pragma unroll
    for (int r = 0; r < 16; ++r) {
      const int R = (r & 3) + 8 * (r >> 2) + 4 * hi;
      float* orow = outf + (size_t)(row0 + wr * 32 + R) * NE + wc * 128 + lr;
      orow[0]  = acc0[r];
      orow[32] = acc1[r];
      orow[64] = acc2[r];
      orow[96] = acc3[r];
    }
  }
}

// ---------- Kernel 2: chamfer similarity, one wave per (b,q) pair ----------
// R7/R8-verified math. Spill fixes: (a) launch_bounds (256,1): empirically
// hipcc caps VGPR at ~256/arg2 (R7: arg2=3 -> 84; R8: arg2=2 -> 128, both
// spilled ~160-float live set to scratch). (b) offA[4]/offB[4] arrays
// replaced with 4 scalar offsets + compile-time cur/next pick (rule #20:
// runtime-indexed arrays go to scratch if the p-loop isn't unrolled).
__global__ __launch_bounds__(256, 1) void sim_kernel(
    const ushort* __restrict__ vt, const ushort* __restrict__ tfrag,
    const int* __restrict__ tlen,
    float* __restrict__ out_i2t, float* __restrict__ out_t2i) {
  __shared__ ushort t_lds[16384];   // 32 KB: [mt(2)][ks(16)][lane(64)][e(8)]

  const int blk = blockIdx.x;
  const int q = blk & 63;
  const int bc = blk >> 6;          // 0..15
  const int tid = threadIdx.x;

  {  // stage T: frag-order global -> LDS, linear, coalesced, conflict-free
    const bh8* src = (const bh8*)(tfrag + (size_t)q * 16384);
    bh8* dst = (bh8*)t_lds;
#pragma unroll
    for (int j = 0; j < 8; ++j) dst[tid + j * 256] = src[tid + j * 256];
  }
  __syncthreads();

  const int l = tid & 63, w = tid >> 6;
  const int lr = l & 31, hi = l >> 5;
  const int b = bc * 4 + w;
  const int len = tlen[b];
  const ushort* Vb = vt + (size_t)b * NV * NE + hi * 8;

  // scalar stream offsets (A: rows p*64+lr, B: rows p*64+32+lr; clamped)
  int oA = lr * NE;                       // p=0, rows < 64 always valid
  int oB = (32 + lr) * NE;

  bh8 rA[4], rB[4];
#pragma unroll
  for (int s = 0; s < 4; ++s) {
    rA[s] = *(const bh8*)(Vb + oA + s * 16);
    rB[s] = *(const bh8*)(Vb + oB + s * 16);
  }

  f32x16 vmax0, vmax1;
#pragma unroll
  for (int r = 0; r < 16; ++r) { vmax0[r] = -1e30f; vmax1[r] = -1e30f; }
  float i2t_sum = 0.0f;

  for (int p = 0; p < 4; ++p) {
    const int oAn = min((p + 1) * 64 + lr, NV - 1) * NE;       // next subtile
    const int oBn = min((p + 1) * 64 + 32 + lr, NV - 1) * NE;  // (p=3: clamped dup)
    f32x16 a00 = {0}, a01 = {0}, a10 = {0}, a11 = {0};  // [mt][st]
    __builtin_amdgcn_s_setprio(1);
#pragma unroll
    for (int ks = 0; ks < 16; ++ks) {
      bh8 ta0 = *(const bh8*)&t_lds[(size_t)(ks * 64 + l) * 8];
      bh8 ta1 = *(const bh8*)&t_lds[(size_t)((16 + ks) * 64 + l) * 8];
      bh8 vb0 = rA[ks & 3], vb1 = rB[ks & 3];
      const int sn = ks + 4;                     // compile-time after unroll
      if (sn < 16) {
        rA[ks & 3] = *(const bh8*)(Vb + oA + sn * 16);
        rB[ks & 3] = *(const bh8*)(Vb + oB + sn * 16);
      } else {
        rA[ks & 3] = *(const bh8*)(Vb + oAn + (sn - 16) * 16);
        rB[ks & 3] = *(const bh8*)(Vb + oBn + (sn - 16) * 16);
      }
      a00 = __builtin_amdgcn_mfma_f32_32x32x16_bf16(ta0, vb0, a00, 0, 0, 0);
      a01 = __builtin_amdgcn_mfma_f32_32x32x16_bf16(ta0, vb1, a01, 0, 0, 0);
      a10 = __builtin_amdgcn_mfma_f32_32x32x16_bf16(ta1, vb0, a10, 0, 0, 0);
      a11 = __builtin_amdgcn_mfma_f32_32x32x16_bf16(ta1, vb1, a11, 0, 0, 0);
    }
    __builtin_amdgcn_s_setprio(0);
    oA = oAn; oB = oBn;

    // i2t: per-lane v-col, max over t (in-lane 32 els + cross-hi)
    {
      float m0 = fmaxf(a00[0], a10[0]);
#pragma unroll
      for (int r = 1; r < 16; ++r) m0 = fmaxf(m0, fmaxf(a00[r], a10[r]));
      m0 = fmaxf(m0, __shfl_xor(m0, 32));
      if ((p * 64 + lr) < NV && hi == 0) i2t_sum += m0;
      float m1 = fmaxf(a01[0], a11[0]);
#pragma unroll
      for (int r = 1; r < 16; ++r) m1 = fmaxf(m1, fmaxf(a01[r], a11[r]));
      m1 = fmaxf(m1, __shfl_xor(m1, 32));
      if ((p * 64 + 32 + lr) < NV && hi == 0) i2t_sum += m1;
    }
    // t2i: running max over v (clamped dup rows can't change the max)
#pragma unroll
    for (int r = 0; r < 16; ++r) {
      vmax0[r] = fmaxf(vmax0[r], fmaxf(a00[r], a01[r]));
      vmax1[r] = fmaxf(vmax1[r], fmaxf(a10[r], a11[r]));
    }
  }

  // t2i finalize: one lr-butterfly per pair
#pragma unroll
  for (int off = 1; off < 32; off <<= 1) {
#pragma unroll
    for (int r = 0; r < 16; ++r) {
      vmax0[r] = fmaxf(vmax0[r], __shfl_xor(vmax0[r], off));
      vmax1[r] = fmaxf(vmax1[r], __shfl_xor(vmax1[r], off));
    }
  }
  float tsum = 0.0f;
#pragma unroll
  for (int r = 0; r < 16; ++r) {
    const int t0 = (r & 3) + 8 * (r >> 2) + 4 * hi;
    if (t0 < len) tsum += vmax0[r];
    if (32 + t0 < len) tsum += vmax1[r];
  }
  tsum += __shfl_xor(tsum, 32);

#pragma unroll
  for (int off = 1; off < 64; off <<= 1) i2t_sum += __shfl_xor(i2t_sum, off);

  if (l == 0) {
    out_t2i[b * NB + q] = tsum / fmaxf((float)len, 1e-6f);
    out_i2t[b * NB + q] = i2t_sum / (float)NV;
  }
}

extern "C" void kernel_launch(void* const* d_in, const int* in_sizes, int n_in,
                              void* d_out, int out_size, void* d_ws, size_t ws_size,
                              hipStream_t stream) {
  (void)in_sizes; (void)n_in; (void)out_size; (void)ws_size;
  const float* visual_cls    = (const float*)d_in[0];
  const float* textual_cls   = (const float*)d_in[1];
  const float* visual_tokens = (const float*)d_in[2];
  const float* textual_tokens= (const float*)d_in[3];
  const int*   text_length   = (const int*)d_in[4];
  const float* Wv  = (const float*)d_in[5];
  const float* bv  = (const float*)d_in[6];
  const float* Wt  = (const float*)d_in[7];
  const float* bt  = (const float*)d_in[8];
  const float* Wvt = (const float*)d_in[9];
  const float* bvt = (const float*)d_in[10];
  const float* Wtt = (const float*)d_in[11];
  const float* btt = (const float*)d_in[12];

  float* out   = (float*)d_out;
  float* v_cls = out;                       // 64*256
  float* t_cls = out + NB * NE;             // 64*256
  float* i2t   = out + 2 * NB * NE;         // 64*64
  float* t2i   = i2t + NB * NB;             // 64*64

  ushort* wsb    = (ushort*)d_ws;
  ushort* v_tok  = wsb;                                  // 12608*256 bf16
  ushort* t_frag = v_tok + (size_t)NB * NV * NE;         // 64 q * 16384 (frag order)
  ushort* Fv     = t_frag + (size_t)NB * NL * NE;        // 8*48*64*8 each
  ushort* Ft     = Fv + (size_t)8 * 48 * 64 * 8;
  ushort* Fcv    = Ft + (size_t)8 * 48 * 64 * 8;
  ushort* Fct    = Fcv + (size_t)8 * 48 * 64 * 8;

  wcvt_kernel<<<dim3(48, 4), 256, 0, stream>>>(Wvt, Wtt, Wv, Wt,
                                               Fv, Ft, Fcv, Fct);
  proj_kernel<<<263, 256, 0, stream>>>(visual_tokens, textual_tokens,
                                       visual_cls, textual_cls,
                                       Fv, Ft, Fcv, Fct,
                                       bvt, btt, bv, bt,
                                       v_tok, t_frag, v_cls, t_cls);
  sim_kernel<<<NB * NB / 4, 256, 0, stream>>>(v_tok, t_frag,
                                              text_length, i2t, t2i);
}